// Round 1
// baseline (335.808 us; speedup 1.0000x reference)
//
#include <hip/hip_runtime.h>

#define HD 64
#define SEQLEN 512
#define NBATCH 256

// ---------------------------------------------------------------------------
// k0: transpose w1 [64][128] -> w1t [128][64] so columns are contiguous for
// wave-uniform scalar loads in k1.
// ---------------------------------------------------------------------------
__global__ __launch_bounds__(256) void k0_transpose(const float* __restrict__ w1,
                                                    float* __restrict__ w1t) {
    int t = blockIdx.x * 256 + threadIdx.x;
    if (t < 64 * 128) {
        int i = t >> 7;      // row in w1   (0..63)
        int j = t & 127;     // col in w1   (0..127)
        w1t[j * 64 + i] = w1[t];
    }
}

// ---------------------------------------------------------------------------
// k1: one thread per token. embed gather -> MLP -> residual -> LayerNorm.
// Writes K[token][64] (LN output) and RN[token] = 1/max(||k||, 1e-12).
// All weight accesses are wave-uniform -> scalar loads; h/x stay in VGPRs.
// ---------------------------------------------------------------------------
__global__ __launch_bounds__(256) void k1_token(
    const int* __restrict__ seq, const float* __restrict__ embed,
    const float* __restrict__ w1t, const float* __restrict__ b1,
    const float* __restrict__ w2, const float* __restrict__ b2,
    const float* __restrict__ ln_g, const float* __restrict__ ln_b,
    float* __restrict__ Kout, float* __restrict__ RN)
{
    const int token = blockIdx.x * 256 + threadIdx.x;   // grid sized exactly

    const int idx = seq[token];
    float h[64];
    const float4* er = reinterpret_cast<const float4*>(embed + idx * 64);
#pragma unroll
    for (int i = 0; i < 16; ++i) {
        float4 v = er[i];
        h[4 * i + 0] = v.x; h[4 * i + 1] = v.y;
        h[4 * i + 2] = v.z; h[4 * i + 3] = v.w;
    }

    float x[64];
#pragma unroll
    for (int m = 0; m < 64; ++m) x[m] = b2[m];

    // ff = relu(h @ w1 + b1) @ w2 ; accumulated j-major so t1 is never stored.
#pragma unroll 2
    for (int j = 0; j < 128; ++j) {
        const float* w1r = w1t + j * 64;   // uniform address -> s_load
        float a0 = 0.f, a1 = 0.f, a2 = 0.f, a3 = 0.f;
#pragma unroll
        for (int i = 0; i < 64; i += 4) {
            a0 = fmaf(h[i + 0], w1r[i + 0], a0);
            a1 = fmaf(h[i + 1], w1r[i + 1], a1);
            a2 = fmaf(h[i + 2], w1r[i + 2], a2);
            a3 = fmaf(h[i + 3], w1r[i + 3], a3);
        }
        float acc = fmaxf(b1[j] + ((a0 + a1) + (a2 + a3)), 0.f);
        const float* w2r = w2 + j * 64;    // uniform address -> s_load
#pragma unroll
        for (int m = 0; m < 64; ++m) x[m] = fmaf(acc, w2r[m], x[m]);
    }

    // residual
#pragma unroll
    for (int m = 0; m < 64; ++m) x[m] += h[m];

    // LayerNorm (lane-local, population variance)
    float s0 = 0.f, s1 = 0.f;
#pragma unroll
    for (int m = 0; m < 64; m += 2) { s0 += x[m]; s1 += x[m + 1]; }
    float mu = (s0 + s1) * (1.f / 64.f);
    float v0 = 0.f, v1 = 0.f;
#pragma unroll
    for (int m = 0; m < 64; m += 2) {
        float d0 = x[m] - mu, d1 = x[m + 1] - mu;
        v0 = fmaf(d0, d0, v0);
        v1 = fmaf(d1, d1, v1);
    }
    float var = (v0 + v1) * (1.f / 64.f);
    float rstd = 1.f / sqrtf(var + 1e-5f);

    float ss0 = 0.f, ss1 = 0.f;
#pragma unroll
    for (int m = 0; m < 64; ++m) {
        float k = fmaf((x[m] - mu) * rstd, ln_g[m], ln_b[m]);
        x[m] = k;
        if (m & 1) ss1 = fmaf(k, k, ss1); else ss0 = fmaf(k, k, ss0);
    }
    float nrm = sqrtf(ss0 + ss1);
    float rn = 1.f / fmaxf(nrm, 1e-12f);

    float4* kr = reinterpret_cast<float4*>(Kout + (size_t)token * 64);
#pragma unroll
    for (int i = 0; i < 16; ++i)
        kr[i] = make_float4(x[4 * i + 0], x[4 * i + 1], x[4 * i + 2], x[4 * i + 3]);
    RN[token] = rn;
}

// ---------------------------------------------------------------------------
// k2: delta-rule scan. One block (512 threads) per batch. Thread t owns
// M[r][c0..c0+7], r = t>>3, c0 = 8*(t&7). M in registers; k-rows prefetched.
// Reduction for vp is a 3-stage shfl_xor butterfly within the 8-lane group.
// ---------------------------------------------------------------------------
__global__ __launch_bounds__(512) void k2_scan(
    const float* __restrict__ K, const float* __restrict__ RN,
    float* __restrict__ Y)
{
    const int b = blockIdx.x;
    const int tid = threadIdx.x;
    const int r  = tid >> 3;     // row 0..63
    const int cg = tid & 7;      // column group 0..7

    const float* Kb  = K + (size_t)b * (SEQLEN * 64);
    const float* Kc  = Kb + cg * 8;
    const float* Kr  = Kb + r;
    const float* RNb = RN + b * SEQLEN;

    float M0 = 0.f, M1 = 0.f, M2 = 0.f, M3 = 0.f;
    float M4 = 0.f, M5 = 0.f, M6 = 0.f, M7 = 0.f;

    float4 ca = *reinterpret_cast<const float4*>(Kc);
    float4 cb = *reinterpret_cast<const float4*>(Kc + 4);
    float kr = *Kr;
    float rn = RNb[0];

    for (int l = 0; l < SEQLEN - 1; ++l) {
        // prefetch next key row (row 511 = query on last iteration)
        const float* nx = Kc + (l + 1) * 64;
        float4 na = *reinterpret_cast<const float4*>(nx);
        float4 nb = *reinterpret_cast<const float4*>(nx + 4);
        float nkr = Kr[(l + 1) * 64];
        float nrn = RNb[l + 1];

        float k0 = ca.x * rn, k1 = ca.y * rn, k2 = ca.z * rn, k3 = ca.w * rn;
        float k4 = cb.x * rn, k5 = cb.y * rn, k6 = cb.z * rn, k7 = cb.w * rn;

        float p0 = fmaf(M0, k0, fmaf(M1, k1, fmaf(M2, k2, M3 * k3)));
        float p1 = fmaf(M4, k4, fmaf(M5, k5, fmaf(M6, k6, M7 * k7)));
        float vp = p0 + p1;
        vp += __shfl_xor(vp, 1);
        vp += __shfl_xor(vp, 2);
        vp += __shfl_xor(vp, 4);

        float dv = kr - vp;

        M0 = fmaf(dv, k0, M0); M1 = fmaf(dv, k1, M1);
        M2 = fmaf(dv, k2, M2); M3 = fmaf(dv, k3, M3);
        M4 = fmaf(dv, k4, M4); M5 = fmaf(dv, k5, M5);
        M6 = fmaf(dv, k6, M6); M7 = fmaf(dv, k7, M7);

        ca = na; cb = nb; kr = nkr; rn = nrn;
    }

    // ca/cb now hold row 511 (the LN'd last token) = query
    float y = fmaf(M0, ca.x, fmaf(M1, ca.y, fmaf(M2, ca.z, fmaf(M3, ca.w,
              fmaf(M4, cb.x, fmaf(M5, cb.y, fmaf(M6, cb.z, M7 * cb.w)))))));
    y += __shfl_xor(y, 1);
    y += __shfl_xor(y, 2);
    y += __shfl_xor(y, 4);
    if (cg == 0) Y[b * 64 + r] = y;
}

// ---------------------------------------------------------------------------
// k3: out = (y @ rp_w + rp_b) @ out_w + out_b, per batch. 64 threads/block.
// ---------------------------------------------------------------------------
__global__ __launch_bounds__(64) void k3_head(
    const float* __restrict__ Y, const float* __restrict__ rp_w,
    const float* __restrict__ rp_b, const float* __restrict__ out_w,
    const float* __restrict__ out_b, float* __restrict__ out)
{
    const int b = blockIdx.x;
    const int lane = threadIdx.x;
    __shared__ float sy[64];
    __shared__ float sz[64];

    sy[lane] = Y[b * 64 + lane];
    __syncthreads();

    float z = rp_b[lane];
#pragma unroll
    for (int j = 0; j < 64; ++j) z = fmaf(sy[j], rp_w[j * 64 + lane], z);
    sz[lane] = z;
    __syncthreads();

    float o = out_b[lane];
#pragma unroll
    for (int i = 0; i < 64; ++i) o = fmaf(sz[i], out_w[i * 64 + lane], o);
    out[b * 64 + lane] = o;
}

// ---------------------------------------------------------------------------
extern "C" void kernel_launch(void* const* d_in, const int* in_sizes, int n_in,
                              void* d_out, int out_size, void* d_ws, size_t ws_size,
                              hipStream_t stream) {
    const int*   seq   = (const int*)d_in[0];
    const float* embed = (const float*)d_in[1];
    const float* w1    = (const float*)d_in[2];
    const float* b1    = (const float*)d_in[3];
    const float* w2    = (const float*)d_in[4];
    const float* b2    = (const float*)d_in[5];
    const float* ln_g  = (const float*)d_in[6];
    const float* ln_b  = (const float*)d_in[7];
    const float* rp_w  = (const float*)d_in[8];
    const float* rp_b  = (const float*)d_in[9];
    const float* out_w = (const float*)d_in[10];
    const float* out_b = (const float*)d_in[11];
    float* out = (float*)d_out;

    float* wsf = (float*)d_ws;
    float* w1t = wsf;                      // 128*64          = 8192 floats
    float* K   = wsf + 8192;               // 256*512*64      = 8388608 floats
    float* RN  = K + 8388608;              // 256*512         = 131072 floats
    float* Y   = RN + 131072;              // 256*64          = 16384 floats

    k0_transpose<<<32, 256, 0, stream>>>(w1, w1t);
    k1_token<<<512, 256, 0, stream>>>(seq, embed, w1t, b1, w2, b2,
                                      ln_g, ln_b, K, RN);
    k2_scan<<<NBATCH, 512, 0, stream>>>(K, RN, Y);
    k3_head<<<NBATCH, 64, 0, stream>>>(Y, rp_w, rp_b, out_w, out_b, out);
}